// Round 4
// baseline (90.806 us; speedup 1.0000x reference)
//
#include <hip/hip_runtime.h>
#include <cstddef>

#define HW 4096

typedef __attribute__((ext_vector_type(8))) short short8v;   // 8 bf16
typedef __attribute__((ext_vector_type(4))) float f32x4;     // 4 fp32

__device__ inline unsigned short f2bf(float f) {
    unsigned int u = __float_as_uint(f);
    u += 0x7FFFu + ((u >> 16) & 1u);
    return (unsigned short)(u >> 16);
}
__device__ inline float bf2f(unsigned short s) {
    return __uint_as_float(((unsigned int)s) << 16);
}

#define GLOAD_LDS16(gp, lp) __builtin_amdgcn_global_load_lds( \
    (const __attribute__((address_space(1))) unsigned int*)(gp), \
    (__attribute__((address_space(3))) unsigned int*)(lp), 16, 0, 0)

// ---------------------------------------------------------------------------
// Stage one 128x64 bf16 tile (rows of 64 bf16 = 128B) from row-major [*][256]
// global into LDS, inverse-swizzled source so swizzled ds_read_b128
// (byte ^= (row&7)<<4) is bank-conflict-free.
// ---------------------------------------------------------------------------
__device__ inline void stage_tile(const unsigned short* __restrict__ g,
                                  unsigned short* lds, int kc, int wid, int lane)
{
    const int r8   = lane >> 3;               // row within 8-row group
    const int slot = (lane & 7) ^ r8;         // inverse-swizzled 16B slot
    const unsigned short* src = g + (wid * 32 + r8) * 256 + kc + slot * 8;
#pragma unroll
    for (int i = 0; i < 4; ++i) {
        GLOAD_LDS16(src + i * 8 * 256, lds + (wid * 32 + i * 8) * 64);
    }
}

// read one MFMA A/B fragment (8 bf16) from a [128][64] bf16 LDS tile
__device__ inline short8v read_frag(const unsigned short* lds, int row, int kbyte, int lane)
{
    const char* p = (const char*)lds + row * 128 + (kbyte ^ ((lane & 7) * 16));
    return *(const short8v*)p;
}

// ---------------------------------------------------------------------------
// Prep: bf16 weights (row-major), lo-plane for aux weights, fp32 bias vector.
// wcat_bf[384][256]: rows 0-255 w_val, 256-319 w_off, 320-351 w_attn, 352-383 zero
// ---------------------------------------------------------------------------
__global__ __launch_bounds__(256)
void prep_kernel(const float* __restrict__ w_off, const float* __restrict__ b_off,
                 const float* __restrict__ w_attn, const float* __restrict__ b_attn,
                 const float* __restrict__ w_val, const float* __restrict__ b_val,
                 const float* __restrict__ w_out,
                 unsigned short* __restrict__ wcat_bf, unsigned short* __restrict__ wauxlo,
                 unsigned short* __restrict__ wout_bf, float* __restrict__ bcat)
{
    int i = blockIdx.x * 256 + threadIdx.x;
    if (i < 384 * 256) {
        int n = i >> 8, k = i & 255;
        float v;
        if (n < 256)      v = w_val[n * 256 + k];
        else if (n < 320) v = w_off[(n - 256) * 256 + k];
        else if (n < 352) v = w_attn[(n - 320) * 256 + k];
        else              v = 0.0f;
        unsigned short hi = f2bf(v);
        wcat_bf[i] = hi;
        if (n >= 256) wauxlo[(n - 256) * 256 + k] = f2bf(v - bf2f(hi));
    }
    if (i < 256 * 256) wout_bf[i] = f2bf(w_out[i]);
    if (i < 512) {
        float v = 0.0f;
        if (i < 256)      v = b_val[i];
        else if (i < 320) v = b_off[i - 256];
        else if (i < 352) v = b_attn[i - 320];
        bcat[i] = v;
    }
}

// ---------------------------------------------------------------------------
// Transpose x: fp32 [b][c][4096] -> bf16 hi/lo [b][p][256]
// ---------------------------------------------------------------------------
__global__ __launch_bounds__(256)
void transpose_kernel(const float* __restrict__ x,
                      unsigned short* __restrict__ xhi, unsigned short* __restrict__ xlo)
{
    __shared__ float t[64][65];
    const int bid = blockIdx.x;
    const int pt = bid & 63, ct = (bid >> 6) & 3, b = bid >> 8;
    const int tid = threadIdx.x;
    const int rr = tid >> 4, c4 = (tid & 15) * 4;

    const float* src = x + ((size_t)(b * 256 + ct * 64)) * HW + pt * 64;
#pragma unroll
    for (int j = 0; j < 4; ++j) {
        float4 v = *(const float4*)&src[(size_t)(j * 16 + rr) * HW + c4];
        t[j * 16 + rr][c4 + 0] = v.x; t[j * 16 + rr][c4 + 1] = v.y;
        t[j * 16 + rr][c4 + 2] = v.z; t[j * 16 + rr][c4 + 3] = v.w;
    }
    __syncthreads();

    const size_t obase = ((size_t)b * HW + pt * 64) * 256 + ct * 64;
#pragma unroll
    for (int j = 0; j < 4; ++j) {
        int p = j * 16 + rr;
        float f0 = t[c4 + 0][p], f1 = t[c4 + 1][p], f2 = t[c4 + 2][p], f3 = t[c4 + 3][p];
        ushort4 hi = make_ushort4(f2bf(f0), f2bf(f1), f2bf(f2), f2bf(f3));
        ushort4 lo = make_ushort4(f2bf(f0 - bf2f(hi.x)), f2bf(f1 - bf2f(hi.y)),
                                  f2bf(f2 - bf2f(hi.z)), f2bf(f3 - bf2f(hi.w)));
        *(ushort4*)&xhi[obase + (size_t)p * 256 + c4] = hi;
        *(ushort4*)&xlo[obase + (size_t)p * 256 + c4] = lo;
    }
}

// ---------------------------------------------------------------------------
// 2-phase pipelined MFMA mainloop: 128x128 tile, K=256 in 4 chunks of 64,
// double-buffered LDS; next chunk's global_load_lds issued BEFORE computing
// the current chunk (T3 minimum 2-phase).
// ---------------------------------------------------------------------------
__device__ inline void mfma_loop2(const unsigned short* __restrict__ Ag,
                                  const unsigned short* __restrict__ Bg,
                                  unsigned short (*Al)[128 * 64], unsigned short (*Bl)[128 * 64],
                                  int wid, int lane, int wm, int wn, f32x4 acc[4][4])
{
    const int mloc = lane & 15, ksel = lane >> 4;

    stage_tile(Ag, Al[0], 0, wid, lane);
    stage_tile(Bg, Bl[0], 0, wid, lane);
    __syncthreads();

#pragma unroll
    for (int kc = 0; kc < 4; ++kc) {
        const int cur = kc & 1;
        if (kc < 3) {
            stage_tile(Ag, Al[cur ^ 1], (kc + 1) * 64, wid, lane);
            stage_tile(Bg, Bl[cur ^ 1], (kc + 1) * 64, wid, lane);
        }
#pragma unroll
        for (int kk = 0; kk < 2; ++kk) {
            const int kb = kk * 64 + ksel * 16;
            short8v a[4], bb[4];
#pragma unroll
            for (int f = 0; f < 4; ++f) a[f]  = read_frag(Al[cur], wm * 64 + f * 16 + mloc, kb, lane);
#pragma unroll
            for (int f = 0; f < 4; ++f) bb[f] = read_frag(Bl[cur], wn * 64 + f * 16 + mloc, kb, lane);
#pragma unroll
            for (int fm = 0; fm < 4; ++fm)
#pragma unroll
                for (int fn = 0; fn < 4; ++fn)
                    acc[fm][fn] = __builtin_amdgcn_mfma_f32_16x16x32_bf16(a[fm], bb[fn], acc[fm][fn], 0, 0, 0);
        }
        __syncthreads();
    }
}

// ---------------------------------------------------------------------------
// GEMM1a: value projection. grid = 8(b) * 2(mt) * 32(pt) = 512.
// ---------------------------------------------------------------------------
__global__ __launch_bounds__(256)
void value_gemm(const unsigned short* __restrict__ wcat_bf, const unsigned short* __restrict__ xhi,
                const float* __restrict__ bcat, unsigned short* __restrict__ value_bf)
{
    __shared__ unsigned short Al[2][128 * 64];
    __shared__ unsigned short Bl[2][128 * 64];
    const int bid = blockIdx.x;
    const int pt = bid & 31, mt = (bid >> 5) & 1, b = bid >> 6;
    const int tid = threadIdx.x, wid = tid >> 6, lane = tid & 63;
    const int wm = wid >> 1, wn = wid & 1;
    const int mloc = lane & 15, ksel = lane >> 4;

    const unsigned short* Ag = wcat_bf + mt * 128 * 256;
    const unsigned short* Bg = xhi + ((size_t)b * HW + pt * 128) * 256;

    f32x4 acc[4][4];
#pragma unroll
    for (int fm = 0; fm < 4; ++fm) {
        float4 bv = *(const float4*)&bcat[mt * 128 + wm * 64 + fm * 16 + ksel * 4];
#pragma unroll
        for (int fn = 0; fn < 4; ++fn) acc[fm][fn] = (f32x4){bv.x, bv.y, bv.z, bv.w};
    }

    mfma_loop2(Ag, Bg, Al, Bl, wid, lane, wm, wn, acc);

#pragma unroll
    for (int fm = 0; fm < 4; ++fm) {
        const int ch = mt * 128 + wm * 64 + fm * 16 + ksel * 4;
        const int head = ch >> 5, c32 = ch & 31;
#pragma unroll
        for (int fn = 0; fn < 4; ++fn) {
            const int p = pt * 128 + wn * 64 + fn * 16 + mloc;
            f32x4 v = acc[fm][fn];
            ushort4 st = make_ushort4(f2bf(v[0]), f2bf(v[1]), f2bf(v[2]), f2bf(v[3]));
            *(ushort4*)&value_bf[(((size_t)(b * 8 + head)) * HW + p) * 32 + c32] = st;
        }
    }
}

// ---------------------------------------------------------------------------
// GEMM1b: offsets+attn with split-bf16 (3-term), 2-phase pipelined.
// grid = 8(b) * 32(pt) = 256. LDS 128KB (8 x 16KB tiles).
// ---------------------------------------------------------------------------
__global__ __launch_bounds__(256)
void offattn_gemm(const unsigned short* __restrict__ wcat_bf, const unsigned short* __restrict__ wauxlo,
                  const unsigned short* __restrict__ xhi, const unsigned short* __restrict__ xlo,
                  const float* __restrict__ bcat,
                  float* __restrict__ off_ws, float* __restrict__ attn_ws)
{
    __shared__ unsigned short Ah[2][128 * 64];
    __shared__ unsigned short Alo[2][128 * 64];
    __shared__ unsigned short Bh[2][128 * 64];
    __shared__ unsigned short Blo[2][128 * 64];
    const int bid = blockIdx.x;
    const int pt = bid & 31, b = bid >> 5;
    const int tid = threadIdx.x, wid = tid >> 6, lane = tid & 63;
    const int wm = wid >> 1, wn = wid & 1;
    const int mloc = lane & 15, ksel = lane >> 4;

    const unsigned short* Ahg = wcat_bf + 256 * 256;          // aux rows 256..383
    const unsigned short* Alg = wauxlo;
    const unsigned short* Bhg = xhi + ((size_t)b * HW + pt * 128) * 256;
    const unsigned short* Blg = xlo + ((size_t)b * HW + pt * 128) * 256;

    f32x4 acc[4][4];
#pragma unroll
    for (int fm = 0; fm < 4; ++fm) {
        float4 bv = *(const float4*)&bcat[256 + wm * 64 + fm * 16 + ksel * 4];
#pragma unroll
        for (int fn = 0; fn < 4; ++fn) acc[fm][fn] = (f32x4){bv.x, bv.y, bv.z, bv.w};
    }

    stage_tile(Ahg, Ah[0], 0, wid, lane);
    stage_tile(Alg, Alo[0], 0, wid, lane);
    stage_tile(Bhg, Bh[0], 0, wid, lane);
    stage_tile(Blg, Blo[0], 0, wid, lane);
    __syncthreads();

#pragma unroll
    for (int kc = 0; kc < 4; ++kc) {
        const int cur = kc & 1;
        if (kc < 3) {
            stage_tile(Ahg, Ah[cur ^ 1], (kc + 1) * 64, wid, lane);
            stage_tile(Alg, Alo[cur ^ 1], (kc + 1) * 64, wid, lane);
            stage_tile(Bhg, Bh[cur ^ 1], (kc + 1) * 64, wid, lane);
            stage_tile(Blg, Blo[cur ^ 1], (kc + 1) * 64, wid, lane);
        }
#pragma unroll
        for (int kk = 0; kk < 2; ++kk) {
            const int kb = kk * 64 + ksel * 16;
            short8v ah[4], al[4], bh[4], bl[4];
#pragma unroll
            for (int f = 0; f < 4; ++f) {
                ah[f] = read_frag(Ah[cur],  wm * 64 + f * 16 + mloc, kb, lane);
                al[f] = read_frag(Alo[cur], wm * 64 + f * 16 + mloc, kb, lane);
                bh[f] = read_frag(Bh[cur],  wn * 64 + f * 16 + mloc, kb, lane);
                bl[f] = read_frag(Blo[cur], wn * 64 + f * 16 + mloc, kb, lane);
            }
#pragma unroll
            for (int fm = 0; fm < 4; ++fm)
#pragma unroll
                for (int fn = 0; fn < 4; ++fn) {
                    acc[fm][fn] = __builtin_amdgcn_mfma_f32_16x16x32_bf16(ah[fm], bh[fn], acc[fm][fn], 0, 0, 0);
                    acc[fm][fn] = __builtin_amdgcn_mfma_f32_16x16x32_bf16(ah[fm], bl[fn], acc[fm][fn], 0, 0, 0);
                    acc[fm][fn] = __builtin_amdgcn_mfma_f32_16x16x32_bf16(al[fm], bh[fn], acc[fm][fn], 0, 0, 0);
                }
        }
        __syncthreads();
    }

#pragma unroll
    for (int fm = 0; fm < 4; ++fm) {
        const int chb = wm * 64 + fm * 16 + ksel * 4;
#pragma unroll
        for (int fn = 0; fn < 4; ++fn) {
            const int p = pt * 128 + wn * 64 + fn * 16 + mloc;
            f32x4 v = acc[fm][fn];
#pragma unroll
            for (int r = 0; r < 4; ++r) {
                int ch = chb + r;
                if (ch < 64)       off_ws[((size_t)(b * 64 + ch)) * HW + p] = v[r];
                else if (ch < 96)  attn_ws[((size_t)(b * 32 + (ch - 64))) * HW + p] = v[r];
            }
        }
    }
}

// ---------------------------------------------------------------------------
// Sampling: softmax(P=4) + bilinear gather + weighted sum.
// 8 lanes/position. Writes bf16 wgt_t[b][p][256]. grid = 8192
// ---------------------------------------------------------------------------
__global__ __launch_bounds__(256)
void sample_kernel(const unsigned short* __restrict__ value_bf, const float* __restrict__ off_ws,
                   const float* __restrict__ attn_ws, unsigned short* __restrict__ wgt_t)
{
    const int bid    = blockIdx.x;
    const int ptile  = bid & 127;
    const int head   = (bid >> 7) & 7;
    const int b      = bid >> 10;
    const int tid    = threadIdx.x;
    const int c4     = tid & 7;
    const int posIdx = tid >> 3;
    const int p      = ptile * 32 + posIdx;
    const int h      = p >> 6;
    const int w      = p & 63;

    const float gx = w * (2.0f / 63.0f) - 1.0f;
    const float gy = h * (2.0f / 63.0f) - 1.0f;

    float l0 = attn_ws[(size_t)(b * 32 + head * 4 + 0) * HW + p];
    float l1 = attn_ws[(size_t)(b * 32 + head * 4 + 1) * HW + p];
    float l2 = attn_ws[(size_t)(b * 32 + head * 4 + 2) * HW + p];
    float l3 = attn_ws[(size_t)(b * 32 + head * 4 + 3) * HW + p];
    float m  = fmaxf(fmaxf(l0, l1), fmaxf(l2, l3));
    float e0 = __expf(l0 - m), e1 = __expf(l1 - m), e2 = __expf(l2 - m), e3 = __expf(l3 - m);
    float inv = 1.0f / (e0 + e1 + e2 + e3);
    float aw[4] = {e0 * inv, e1 * inv, e2 * inv, e3 * inv};

    float4 acc = make_float4(0.f, 0.f, 0.f, 0.f);
    const unsigned short* vb = value_bf + (size_t)(b * 8 + head) * HW * 32 + c4 * 4;

#pragma unroll
    for (int pt = 0; pt < 4; ++pt) {
        float ox = off_ws[(size_t)(b * 64 + (head * 4 + pt) * 2 + 0) * HW + p];
        float oy = off_ws[(size_t)(b * 64 + (head * 4 + pt) * 2 + 1) * HW + p];
        float ix = (gx + ox + 1.0f) * 31.5f;
        float iy = (gy + oy + 1.0f) * 31.5f;
        float x0f = floorf(ix), y0f = floorf(iy);
        float wx1 = ix - x0f, wx0 = 1.0f - wx1;
        float wy1 = iy - y0f, wy0 = 1.0f - wy1;
        int x0 = (int)x0f, y0 = (int)y0f;
        int x1 = x0 + 1,   y1 = y0 + 1;
        float a = aw[pt];
        float vx0 = (x0 >= 0 && x0 <= 63) ? 1.f : 0.f;
        float vx1 = (x1 >= 0 && x1 <= 63) ? 1.f : 0.f;
        float vy0 = (y0 >= 0 && y0 <= 63) ? 1.f : 0.f;
        float vy1 = (y1 >= 0 && y1 <= 63) ? 1.f : 0.f;
        float w00 = a * wy0 * wx0 * vy0 * vx0;
        float w01 = a * wy0 * wx1 * vy0 * vx1;
        float w10 = a * wy1 * wx0 * vy1 * vx0;
        float w11 = a * wy1 * wx1 * vy1 * vx1;
        int cx0 = min(max(x0, 0), 63), cx1 = min(max(x1, 0), 63);
        int cy0 = min(max(y0, 0), 63), cy1 = min(max(y1, 0), 63);
        ushort4 u00 = *(const ushort4*)&vb[(size_t)(cy0 * 64 + cx0) * 32];
        ushort4 u01 = *(const ushort4*)&vb[(size_t)(cy0 * 64 + cx1) * 32];
        ushort4 u10 = *(const ushort4*)&vb[(size_t)(cy1 * 64 + cx0) * 32];
        ushort4 u11 = *(const ushort4*)&vb[(size_t)(cy1 * 64 + cx1) * 32];
        acc.x += w00 * bf2f(u00.x) + w01 * bf2f(u01.x) + w10 * bf2f(u10.x) + w11 * bf2f(u11.x);
        acc.y += w00 * bf2f(u00.y) + w01 * bf2f(u01.y) + w10 * bf2f(u10.y) + w11 * bf2f(u11.y);
        acc.z += w00 * bf2f(u00.z) + w01 * bf2f(u01.z) + w10 * bf2f(u10.z) + w11 * bf2f(u11.z);
        acc.w += w00 * bf2f(u00.w) + w01 * bf2f(u01.w) + w10 * bf2f(u10.w) + w11 * bf2f(u11.w);
    }

    ushort4 st = make_ushort4(f2bf(acc.x), f2bf(acc.y), f2bf(acc.z), f2bf(acc.w));
    *(ushort4*)&wgt_t[((size_t)b * HW + p) * 256 + head * 32 + c4 * 4] = st;
}

// ---------------------------------------------------------------------------
// GEMM2: output projection + bias + residual. grid = 512
// ---------------------------------------------------------------------------
__global__ __launch_bounds__(256)
void outproj_gemm(const unsigned short* __restrict__ wout_bf, const unsigned short* __restrict__ wgt_t,
                  const float* __restrict__ b_out, const float* __restrict__ x,
                  float* __restrict__ out)
{
    __shared__ unsigned short Al[2][128 * 64];
    __shared__ unsigned short Bl[2][128 * 64];
    const int bid = blockIdx.x;
    const int pt = bid & 31, mt = (bid >> 5) & 1, b = bid >> 6;
    const int tid = threadIdx.x, wid = tid >> 6, lane = tid & 63;
    const int wm = wid >> 1, wn = wid & 1;
    const int mloc = lane & 15, ksel = lane >> 4;

    const unsigned short* Ag = wout_bf + mt * 128 * 256;
    const unsigned short* Bg = wgt_t + ((size_t)b * HW + pt * 128) * 256;

    f32x4 acc[4][4];
#pragma unroll
    for (int fm = 0; fm < 4; ++fm)
#pragma unroll
        for (int fn = 0; fn < 4; ++fn) acc[fm][fn] = (f32x4){0.f, 0.f, 0.f, 0.f};

    mfma_loop2(Ag, Bg, Al, Bl, wid, lane, wm, wn, acc);

#pragma unroll
    for (int fm = 0; fm < 4; ++fm) {
        const int o = mt * 128 + wm * 64 + fm * 16 + ksel * 4;
        float4 bo = *(const float4*)&b_out[o];
#pragma unroll
        for (int fn = 0; fn < 4; ++fn) {
            const int p = pt * 128 + wn * 64 + fn * 16 + mloc;
            const size_t idx = ((size_t)(b * 256 + o)) * HW + p;
            f32x4 v = acc[fm][fn];
            out[idx + 0 * HW] = v[0] + bo.x + x[idx + 0 * HW];
            out[idx + 1 * HW] = v[1] + bo.y + x[idx + 1 * HW];
            out[idx + 2 * HW] = v[2] + bo.z + x[idx + 2 * HW];
            out[idx + 3 * HW] = v[3] + bo.w + x[idx + 3 * HW];
        }
    }
}

// ---------------------------------------------------------------------------
extern "C" void kernel_launch(void* const* d_in, const int* in_sizes, int n_in,
                              void* d_out, int out_size, void* d_ws, size_t ws_size,
                              hipStream_t stream)
{
    const float* x      = (const float*)d_in[0];
    const float* w_off  = (const float*)d_in[1];
    const float* b_off  = (const float*)d_in[2];
    const float* w_attn = (const float*)d_in[3];
    const float* b_attn = (const float*)d_in[4];
    const float* w_val  = (const float*)d_in[5];
    const float* b_val  = (const float*)d_in[6];
    const float* w_out  = (const float*)d_in[7];
    const float* b_out  = (const float*)d_in[8];
    float* out = (float*)d_out;

    char* ws = (char*)d_ws;
    unsigned short* wcat_bf = (unsigned short*)(ws + 0);          //  196608 B
    unsigned short* wauxlo  = (unsigned short*)(ws + 196608);     //   65536 B
    unsigned short* wout_bf = (unsigned short*)(ws + 262144);     //  131072 B
    float*          bcat    = (float*)(ws + 393216);              //    2048 B
    unsigned short* xhi     = (unsigned short*)(ws + 395264);     // 16777216 B
    unsigned short* xlo     = (unsigned short*)(ws + 17172480);   // 16777216 B
    unsigned short* val_bf  = (unsigned short*)(ws + 33949696);   // 16777216 B
    float*          off_ws  = (float*)(ws + 50726912);            //  8388608 B
    float*          attn_ws = (float*)(ws + 59115520);            //  4194304 B
    unsigned short* wgt_t   = (unsigned short*)(ws + 63309824);   // 16777216 B

    prep_kernel<<<384, 256, 0, stream>>>(w_off, b_off, w_attn, b_attn, w_val, b_val,
                                         w_out, wcat_bf, wauxlo, wout_bf, bcat);
    transpose_kernel<<<2048, 256, 0, stream>>>(x, xhi, xlo);
    value_gemm<<<512, 256, 0, stream>>>(wcat_bf, xhi, bcat, val_bf);
    offattn_gemm<<<256, 256, 0, stream>>>(wcat_bf, wauxlo, xhi, xlo, bcat, off_ws, attn_ws);
    sample_kernel<<<8192, 256, 0, stream>>>(val_bf, off_ws, attn_ws, wgt_t);
    outproj_gemm<<<512, 256, 0, stream>>>(wout_bf, wgt_t, b_out, x, out);
}

// Round 5
// 81.526 us; speedup vs baseline: 1.1138x; 1.1138x over previous
//
#include <hip/hip_runtime.h>
#include <cstddef>

#define HW 4096

typedef __attribute__((ext_vector_type(8))) short short8v;   // 8 bf16
typedef __attribute__((ext_vector_type(4))) float f32x4;     // 4 fp32

__device__ inline unsigned short f2bf(float f) {
    unsigned int u = __float_as_uint(f);
    u += 0x7FFFu + ((u >> 16) & 1u);
    return (unsigned short)(u >> 16);
}
__device__ inline float bf2f(unsigned short s) {
    return __uint_as_float(((unsigned int)s) << 16);
}

#define GLOAD_LDS16(gp, lp) __builtin_amdgcn_global_load_lds( \
    (const __attribute__((address_space(1))) unsigned int*)(gp), \
    (__attribute__((address_space(3))) unsigned int*)(lp), 16, 0, 0)

// ---------------------------------------------------------------------------
// Stage one 128x64 bf16 tile (rows of 64 bf16 = 128B) from row-major [*][256]
// global into LDS, inverse-swizzled source so swizzled ds_read_b128
// (byte ^= (row&7)<<4) is bank-conflict-free.
// ---------------------------------------------------------------------------
__device__ inline void stage_tile(const unsigned short* __restrict__ g,
                                  unsigned short* lds, int kc, int wid, int lane)
{
    const int r8   = lane >> 3;               // row within 8-row group
    const int slot = (lane & 7) ^ r8;         // inverse-swizzled 16B slot
    const unsigned short* src = g + (wid * 32 + r8) * 256 + kc + slot * 8;
#pragma unroll
    for (int i = 0; i < 4; ++i) {
        GLOAD_LDS16(src + i * 8 * 256, lds + (wid * 32 + i * 8) * 64);
    }
}

// read one MFMA A/B fragment (8 bf16) from a [128][64] bf16 LDS tile
__device__ inline short8v read_frag(const unsigned short* lds, int row, int kbyte, int lane)
{
    const char* p = (const char*)lds + row * 128 + (kbyte ^ ((lane & 7) * 16));
    return *(const short8v*)p;
}

// ---------------------------------------------------------------------------
// Prep: bf16 weights (row-major), lo-plane for aux weight rows (256-383),
// fp32 bias vector.
// wcat_bf[384][256]: rows 0-255 w_val, 256-319 w_off, 320-351 w_attn, 352-383 zero
// ---------------------------------------------------------------------------
__global__ __launch_bounds__(256)
void prep_kernel(const float* __restrict__ w_off, const float* __restrict__ b_off,
                 const float* __restrict__ w_attn, const float* __restrict__ b_attn,
                 const float* __restrict__ w_val, const float* __restrict__ b_val,
                 const float* __restrict__ w_out,
                 unsigned short* __restrict__ wcat_bf, unsigned short* __restrict__ wauxlo,
                 unsigned short* __restrict__ wout_bf, float* __restrict__ bcat)
{
    int i = blockIdx.x * 256 + threadIdx.x;
    if (i < 384 * 256) {
        int n = i >> 8, k = i & 255;
        float v;
        if (n < 256)      v = w_val[n * 256 + k];
        else if (n < 320) v = w_off[(n - 256) * 256 + k];
        else if (n < 352) v = w_attn[(n - 320) * 256 + k];
        else              v = 0.0f;
        unsigned short hi = f2bf(v);
        wcat_bf[i] = hi;
        if (n >= 256) wauxlo[(n - 256) * 256 + k] = f2bf(v - bf2f(hi));
    }
    if (i < 256 * 256) wout_bf[i] = f2bf(w_out[i]);
    if (i < 512) {
        float v = 0.0f;
        if (i < 256)      v = b_val[i];
        else if (i < 320) v = b_off[i - 256];
        else if (i < 352) v = b_attn[i - 320];
        bcat[i] = v;
    }
}

// ---------------------------------------------------------------------------
// Transpose x: fp32 [b][c][4096] -> bf16 [b][p][256]
// ---------------------------------------------------------------------------
__global__ __launch_bounds__(256)
void transpose_kernel(const float* __restrict__ x, unsigned short* __restrict__ xhi)
{
    __shared__ float t[64][65];
    const int bid = blockIdx.x;
    const int pt = bid & 63, ct = (bid >> 6) & 3, b = bid >> 8;
    const int tid = threadIdx.x;
    const int rr = tid >> 4, c4 = (tid & 15) * 4;

    const float* src = x + ((size_t)(b * 256 + ct * 64)) * HW + pt * 64;
#pragma unroll
    for (int j = 0; j < 4; ++j) {
        float4 v = *(const float4*)&src[(size_t)(j * 16 + rr) * HW + c4];
        t[j * 16 + rr][c4 + 0] = v.x; t[j * 16 + rr][c4 + 1] = v.y;
        t[j * 16 + rr][c4 + 2] = v.z; t[j * 16 + rr][c4 + 3] = v.w;
    }
    __syncthreads();

    const size_t obase = ((size_t)b * HW + pt * 64) * 256 + ct * 64;
#pragma unroll
    for (int j = 0; j < 4; ++j) {
        int p = j * 16 + rr;
        ushort4 hi = make_ushort4(f2bf(t[c4 + 0][p]), f2bf(t[c4 + 1][p]),
                                  f2bf(t[c4 + 2][p]), f2bf(t[c4 + 3][p]));
        *(ushort4*)&xhi[obase + (size_t)p * 256 + c4] = hi;
    }
}

// ---------------------------------------------------------------------------
// Unified projection kernel: value (mt=0,1) + offsets/attn (mt=2).
// grid = 8(b) * 32(pt) * 3(mt) = 768 blocks, mt fastest-varying so XCDs/CUs
// get a mix of MFMA-heavy (value) and load-heavy (aux) blocks co-resident
// (3 blocks/CU at 48KB LDS) — inter-block TLP hides the staging latency.
// Aux uses weight-only split precision: (Wh + Wl) x Xbf16 -> ~fp32 offsets.
// ---------------------------------------------------------------------------
__global__ __launch_bounds__(256)
void proj_kernel(const unsigned short* __restrict__ wcat_bf, const unsigned short* __restrict__ wauxlo,
                 const unsigned short* __restrict__ xhi, const float* __restrict__ bcat,
                 unsigned short* __restrict__ value_bf,
                 float* __restrict__ off_ws, float* __restrict__ attn_ws)
{
    __shared__ unsigned short lds[3 * 128 * 64];   // 48 KB
    const int bid = blockIdx.x;
    const int mt = bid % 3;
    const int pt = (bid / 3) & 31;
    const int b  = bid / 96;
    const int tid = threadIdx.x, wid = tid >> 6, lane = tid & 63;
    const int wm = wid >> 1, wn = wid & 1;
    const int mloc = lane & 15, ksel = lane >> 4;

    const unsigned short* Bg = xhi + ((size_t)b * HW + pt * 128) * 256;

    f32x4 acc[4][4];
#pragma unroll
    for (int fm = 0; fm < 4; ++fm) {
        float4 bv = *(const float4*)&bcat[mt * 128 + wm * 64 + fm * 16 + ksel * 4];
#pragma unroll
        for (int fn = 0; fn < 4; ++fn) acc[fm][fn] = (f32x4){bv.x, bv.y, bv.z, bv.w};
    }

    if (mt < 2) {
        // ---- value path: plain bf16, 2 tiles per chunk ----
        unsigned short* Al = lds;
        unsigned short* Bl = lds + 128 * 64;
        const unsigned short* Ag = wcat_bf + mt * 128 * 256;
#pragma unroll
        for (int kc = 0; kc < 4; ++kc) {
            if (kc) __syncthreads();
            stage_tile(Ag, Al, kc * 64, wid, lane);
            stage_tile(Bg, Bl, kc * 64, wid, lane);
            __syncthreads();
#pragma unroll
            for (int kk = 0; kk < 2; ++kk) {
                const int kb = kk * 64 + ksel * 16;
                short8v a[4], bb[4];
#pragma unroll
                for (int f = 0; f < 4; ++f) a[f]  = read_frag(Al, wm * 64 + f * 16 + mloc, kb, lane);
#pragma unroll
                for (int f = 0; f < 4; ++f) bb[f] = read_frag(Bl, wn * 64 + f * 16 + mloc, kb, lane);
#pragma unroll
                for (int fm = 0; fm < 4; ++fm)
#pragma unroll
                    for (int fn = 0; fn < 4; ++fn)
                        acc[fm][fn] = __builtin_amdgcn_mfma_f32_16x16x32_bf16(a[fm], bb[fn], acc[fm][fn], 0, 0, 0);
            }
        }
        // epilogue: value_bf[(b*8+head)][p][c32]
#pragma unroll
        for (int fm = 0; fm < 4; ++fm) {
            const int ch = mt * 128 + wm * 64 + fm * 16 + ksel * 4;
            const int head = ch >> 5, c32 = ch & 31;
#pragma unroll
            for (int fn = 0; fn < 4; ++fn) {
                const int p = pt * 128 + wn * 64 + fn * 16 + mloc;
                f32x4 v = acc[fm][fn];
                ushort4 st = make_ushort4(f2bf(v[0]), f2bf(v[1]), f2bf(v[2]), f2bf(v[3]));
                *(ushort4*)&value_bf[(((size_t)(b * 8 + head)) * HW + p) * 32 + c32] = st;
            }
        }
    } else {
        // ---- aux path: (Wh + Wl) x Xbf, 3 tiles per chunk ----
        unsigned short* Ah  = lds;
        unsigned short* Alo = lds + 128 * 64;
        unsigned short* Bl  = lds + 2 * 128 * 64;
        const unsigned short* Ahg = wcat_bf + 256 * 256;
        const unsigned short* Alg = wauxlo;
#pragma unroll
        for (int kc = 0; kc < 4; ++kc) {
            if (kc) __syncthreads();
            stage_tile(Ahg, Ah, kc * 64, wid, lane);
            stage_tile(Alg, Alo, kc * 64, wid, lane);
            stage_tile(Bg, Bl, kc * 64, wid, lane);
            __syncthreads();
#pragma unroll
            for (int kk = 0; kk < 2; ++kk) {
                const int kb = kk * 64 + ksel * 16;
                short8v ah[4], al[4], bb[4];
#pragma unroll
                for (int f = 0; f < 4; ++f) {
                    ah[f] = read_frag(Ah,  wm * 64 + f * 16 + mloc, kb, lane);
                    al[f] = read_frag(Alo, wm * 64 + f * 16 + mloc, kb, lane);
                    bb[f] = read_frag(Bl,  wn * 64 + f * 16 + mloc, kb, lane);
                }
#pragma unroll
                for (int fm = 0; fm < 4; ++fm)
#pragma unroll
                    for (int fn = 0; fn < 4; ++fn) {
                        acc[fm][fn] = __builtin_amdgcn_mfma_f32_16x16x32_bf16(ah[fm], bb[fn], acc[fm][fn], 0, 0, 0);
                        acc[fm][fn] = __builtin_amdgcn_mfma_f32_16x16x32_bf16(al[fm], bb[fn], acc[fm][fn], 0, 0, 0);
                    }
            }
        }
        // epilogue: rows 0-63 -> off_ws, 64-95 -> attn_ws, 96-127 pad
#pragma unroll
        for (int fm = 0; fm < 4; ++fm) {
            const int chb = wm * 64 + fm * 16 + ksel * 4;
#pragma unroll
            for (int fn = 0; fn < 4; ++fn) {
                const int p = pt * 128 + wn * 64 + fn * 16 + mloc;
                f32x4 v = acc[fm][fn];
#pragma unroll
                for (int r = 0; r < 4; ++r) {
                    int ch = chb + r;
                    if (ch < 64)      off_ws[((size_t)(b * 64 + ch)) * HW + p] = v[r];
                    else if (ch < 96) attn_ws[((size_t)(b * 32 + (ch - 64))) * HW + p] = v[r];
                }
            }
        }
    }
}

// ---------------------------------------------------------------------------
// Sampling: softmax(P=4) + bilinear gather + weighted sum.
// 8 lanes/position. Writes bf16 wgt_t[b][p][256]. grid = 8192
// ---------------------------------------------------------------------------
__global__ __launch_bounds__(256)
void sample_kernel(const unsigned short* __restrict__ value_bf, const float* __restrict__ off_ws,
                   const float* __restrict__ attn_ws, unsigned short* __restrict__ wgt_t)
{
    const int bid    = blockIdx.x;
    const int ptile  = bid & 127;
    const int head   = (bid >> 7) & 7;
    const int b      = bid >> 10;
    const int tid    = threadIdx.x;
    const int c4     = tid & 7;
    const int posIdx = tid >> 3;
    const int p      = ptile * 32 + posIdx;
    const int h      = p >> 6;
    const int w      = p & 63;

    const float gx = w * (2.0f / 63.0f) - 1.0f;
    const float gy = h * (2.0f / 63.0f) - 1.0f;

    float l0 = attn_ws[(size_t)(b * 32 + head * 4 + 0) * HW + p];
    float l1 = attn_ws[(size_t)(b * 32 + head * 4 + 1) * HW + p];
    float l2 = attn_ws[(size_t)(b * 32 + head * 4 + 2) * HW + p];
    float l3 = attn_ws[(size_t)(b * 32 + head * 4 + 3) * HW + p];
    float m  = fmaxf(fmaxf(l0, l1), fmaxf(l2, l3));
    float e0 = __expf(l0 - m), e1 = __expf(l1 - m), e2 = __expf(l2 - m), e3 = __expf(l3 - m);
    float inv = 1.0f / (e0 + e1 + e2 + e3);
    float aw[4] = {e0 * inv, e1 * inv, e2 * inv, e3 * inv};

    float4 acc = make_float4(0.f, 0.f, 0.f, 0.f);
    const unsigned short* vb = value_bf + (size_t)(b * 8 + head) * HW * 32 + c4 * 4;

#pragma unroll
    for (int pt = 0; pt < 4; ++pt) {
        float ox = off_ws[(size_t)(b * 64 + (head * 4 + pt) * 2 + 0) * HW + p];
        float oy = off_ws[(size_t)(b * 64 + (head * 4 + pt) * 2 + 1) * HW + p];
        float ix = (gx + ox + 1.0f) * 31.5f;
        float iy = (gy + oy + 1.0f) * 31.5f;
        float x0f = floorf(ix), y0f = floorf(iy);
        float wx1 = ix - x0f, wx0 = 1.0f - wx1;
        float wy1 = iy - y0f, wy0 = 1.0f - wy1;
        int x0 = (int)x0f, y0 = (int)y0f;
        int x1 = x0 + 1,   y1 = y0 + 1;
        float a = aw[pt];
        float vx0 = (x0 >= 0 && x0 <= 63) ? 1.f : 0.f;
        float vx1 = (x1 >= 0 && x1 <= 63) ? 1.f : 0.f;
        float vy0 = (y0 >= 0 && y0 <= 63) ? 1.f : 0.f;
        float vy1 = (y1 >= 0 && y1 <= 63) ? 1.f : 0.f;
        float w00 = a * wy0 * wx0 * vy0 * vx0;
        float w01 = a * wy0 * wx1 * vy0 * vx1;
        float w10 = a * wy1 * wx0 * vy1 * vx0;
        float w11 = a * wy1 * wx1 * vy1 * vx1;
        int cx0 = min(max(x0, 0), 63), cx1 = min(max(x1, 0), 63);
        int cy0 = min(max(y0, 0), 63), cy1 = min(max(y1, 0), 63);
        ushort4 u00 = *(const ushort4*)&vb[(size_t)(cy0 * 64 + cx0) * 32];
        ushort4 u01 = *(const ushort4*)&vb[(size_t)(cy0 * 64 + cx1) * 32];
        ushort4 u10 = *(const ushort4*)&vb[(size_t)(cy1 * 64 + cx0) * 32];
        ushort4 u11 = *(const ushort4*)&vb[(size_t)(cy1 * 64 + cx1) * 32];
        acc.x += w00 * bf2f(u00.x) + w01 * bf2f(u01.x) + w10 * bf2f(u10.x) + w11 * bf2f(u11.x);
        acc.y += w00 * bf2f(u00.y) + w01 * bf2f(u01.y) + w10 * bf2f(u10.y) + w11 * bf2f(u11.y);
        acc.z += w00 * bf2f(u00.z) + w01 * bf2f(u01.z) + w10 * bf2f(u10.z) + w11 * bf2f(u11.z);
        acc.w += w00 * bf2f(u00.w) + w01 * bf2f(u01.w) + w10 * bf2f(u10.w) + w11 * bf2f(u11.w);
    }

    ushort4 st = make_ushort4(f2bf(acc.x), f2bf(acc.y), f2bf(acc.z), f2bf(acc.w));
    *(ushort4*)&wgt_t[((size_t)b * HW + p) * 256 + head * 32 + c4 * 4] = st;
}

// ---------------------------------------------------------------------------
// GEMM2: output projection + bias + residual. grid = 512, 32KB LDS
// (single-buffered; up to 4 blocks/CU possible, grid gives 2/CU).
// ---------------------------------------------------------------------------
__global__ __launch_bounds__(256)
void outproj_gemm(const unsigned short* __restrict__ wout_bf, const unsigned short* __restrict__ wgt_t,
                  const float* __restrict__ b_out, const float* __restrict__ x,
                  float* __restrict__ out)
{
    __shared__ unsigned short Al[128 * 64];
    __shared__ unsigned short Bl[128 * 64];
    const int bid = blockIdx.x;
    const int pt = bid & 31, mt = (bid >> 5) & 1, b = bid >> 6;
    const int tid = threadIdx.x, wid = tid >> 6, lane = tid & 63;
    const int wm = wid >> 1, wn = wid & 1;
    const int mloc = lane & 15, ksel = lane >> 4;

    const unsigned short* Ag = wout_bf + mt * 128 * 256;
    const unsigned short* Bg = wgt_t + ((size_t)b * HW + pt * 128) * 256;

    f32x4 acc[4][4];
#pragma unroll
    for (int fm = 0; fm < 4; ++fm)
#pragma unroll
        for (int fn = 0; fn < 4; ++fn) acc[fm][fn] = (f32x4){0.f, 0.f, 0.f, 0.f};

#pragma unroll
    for (int kc = 0; kc < 4; ++kc) {
        if (kc) __syncthreads();
        stage_tile(Ag, Al, kc * 64, wid, lane);
        stage_tile(Bg, Bl, kc * 64, wid, lane);
        __syncthreads();
#pragma unroll
        for (int kk = 0; kk < 2; ++kk) {
            const int kb = kk * 64 + ksel * 16;
            short8v a[4], bb[4];
#pragma unroll
            for (int f = 0; f < 4; ++f) a[f]  = read_frag(Al, wm * 64 + f * 16 + mloc, kb, lane);
#pragma unroll
            for (int f = 0; f < 4; ++f) bb[f] = read_frag(Bl, wn * 64 + f * 16 + mloc, kb, lane);
#pragma unroll
            for (int fm = 0; fm < 4; ++fm)
#pragma unroll
                for (int fn = 0; fn < 4; ++fn)
                    acc[fm][fn] = __builtin_amdgcn_mfma_f32_16x16x32_bf16(a[fm], bb[fn], acc[fm][fn], 0, 0, 0);
        }
    }

#pragma unroll
    for (int fm = 0; fm < 4; ++fm) {
        const int o = mt * 128 + wm * 64 + fm * 16 + ksel * 4;
        float4 bo = *(const float4*)&b_out[o];
#pragma unroll
        for (int fn = 0; fn < 4; ++fn) {
            const int p = pt * 128 + wn * 64 + fn * 16 + mloc;
            const size_t idx = ((size_t)(b * 256 + o)) * HW + p;
            f32x4 v = acc[fm][fn];
            out[idx + 0 * HW] = v[0] + bo.x + x[idx + 0 * HW];
            out[idx + 1 * HW] = v[1] + bo.y + x[idx + 1 * HW];
            out[idx + 2 * HW] = v[2] + bo.z + x[idx + 2 * HW];
            out[idx + 3 * HW] = v[3] + bo.w + x[idx + 3 * HW];
        }
    }
}

// ---------------------------------------------------------------------------
extern "C" void kernel_launch(void* const* d_in, const int* in_sizes, int n_in,
                              void* d_out, int out_size, void* d_ws, size_t ws_size,
                              hipStream_t stream)
{
    const float* x      = (const float*)d_in[0];
    const float* w_off  = (const float*)d_in[1];
    const float* b_off  = (const float*)d_in[2];
    const float* w_attn = (const float*)d_in[3];
    const float* b_attn = (const float*)d_in[4];
    const float* w_val  = (const float*)d_in[5];
    const float* b_val  = (const float*)d_in[6];
    const float* w_out  = (const float*)d_in[7];
    const float* b_out  = (const float*)d_in[8];
    float* out = (float*)d_out;

    char* ws = (char*)d_ws;
    unsigned short* wcat_bf = (unsigned short*)(ws + 0);          //  196608 B
    unsigned short* wauxlo  = (unsigned short*)(ws + 196608);     //   65536 B
    unsigned short* wout_bf = (unsigned short*)(ws + 262144);     //  131072 B
    float*          bcat    = (float*)(ws + 393216);              //    2048 B
    unsigned short* xhi     = (unsigned short*)(ws + 395264);     // 16777216 B
    unsigned short* val_bf  = (unsigned short*)(ws + 17172480);   // 16777216 B
    float*          off_ws  = (float*)(ws + 33949696);            //  8388608 B
    float*          attn_ws = (float*)(ws + 42338304);            //  4194304 B
    unsigned short* wgt_t   = (unsigned short*)(ws + 46532608);   // 16777216 B (end ~63.3 MB)

    prep_kernel<<<384, 256, 0, stream>>>(w_off, b_off, w_attn, b_attn, w_val, b_val,
                                         w_out, wcat_bf, wauxlo, wout_bf, bcat);
    transpose_kernel<<<2048, 256, 0, stream>>>(x, xhi);
    proj_kernel<<<768, 256, 0, stream>>>(wcat_bf, wauxlo, xhi, bcat, val_bf, off_ws, attn_ws);
    sample_kernel<<<8192, 256, 0, stream>>>(val_bf, off_ws, attn_ws, wgt_t);
    outproj_gemm<<<512, 256, 0, stream>>>(wout_bf, wgt_t, b_out, x, out);
}

// Round 6
// 80.728 us; speedup vs baseline: 1.1248x; 1.0099x over previous
//
#include <hip/hip_runtime.h>
#include <cstddef>

#define HW 4096

typedef __attribute__((ext_vector_type(8))) short short8v;   // 8 bf16
typedef __attribute__((ext_vector_type(4))) float f32x4;     // 4 fp32

__device__ inline unsigned short f2bf(float f) {
    unsigned int u = __float_as_uint(f);
    u += 0x7FFFu + ((u >> 16) & 1u);
    return (unsigned short)(u >> 16);
}
__device__ inline float bf2f(unsigned short s) {
    return __uint_as_float(((unsigned int)s) << 16);
}

#define GLOAD_LDS16(gp, lp) __builtin_amdgcn_global_load_lds( \
    (const __attribute__((address_space(1))) unsigned int*)(gp), \
    (__attribute__((address_space(3))) unsigned int*)(lp), 16, 0, 0)

// ---------------------------------------------------------------------------
// Stage a 128-row x 256-bf16 panel (64KB, CONTIGUOUS global span) into LDS.
// Each instruction: 64 lanes x 16B = 1KB fully sequential (2 rows of 512B).
// Source is pre-swizzled (slot ^ (row&15)) so swizzled reads are conflict-lite.
// ---------------------------------------------------------------------------
__device__ inline void stage_panel(const unsigned short* __restrict__ g,
                                   unsigned short* lds, int wid, int lane)
{
    const int rsub = lane >> 5;          // 0/1: which of the 2 rows per instr
    const int slot = lane & 31;          // 16B slot within a 512B row
#pragma unroll
    for (int i = 0; i < 16; ++i) {
        const int row = wid * 32 + i * 2 + rsub;
        GLOAD_LDS16(g + row * 256 + ((slot ^ (row & 15)) << 3),
                    lds + (wid * 32 + i * 2) * 256);
    }
}

// read one MFMA fragment (8 bf16) from a [128][256] bf16 LDS panel
__device__ inline short8v read_frag256(const unsigned short* lds, int row, int kbyte)
{
    const char* p = (const char*)lds + row * 512 + (kbyte ^ ((row & 15) << 4));
    return *(const short8v*)p;
}

// 8 kk-steps over K=256: 16 MFMA per kk for a 64x64 wave tile
__device__ inline void compute_pass(const unsigned short* Al, const unsigned short* Bl,
                                    int wm, int wn, int mloc, int ksel, f32x4 acc[4][4])
{
#pragma unroll
    for (int kk = 0; kk < 8; ++kk) {
        const int kb = kk * 64 + ksel * 16;
        short8v a[4], bb[4];
#pragma unroll
        for (int f = 0; f < 4; ++f) a[f]  = read_frag256(Al, wm * 64 + f * 16 + mloc, kb);
#pragma unroll
        for (int f = 0; f < 4; ++f) bb[f] = read_frag256(Bl, wn * 64 + f * 16 + mloc, kb);
#pragma unroll
        for (int fm = 0; fm < 4; ++fm)
#pragma unroll
            for (int fn = 0; fn < 4; ++fn)
                acc[fm][fn] = __builtin_amdgcn_mfma_f32_16x16x32_bf16(a[fm], bb[fn], acc[fm][fn], 0, 0, 0);
    }
}

// ---------------------------------------------------------------------------
// Prep: bf16 weights (row-major), lo-plane for aux weight rows, fp32 biases.
// wcat_bf[384][256]: rows 0-255 w_val, 256-319 w_off, 320-351 w_attn, 352-383 zero
// ---------------------------------------------------------------------------
__global__ __launch_bounds__(256)
void prep_kernel(const float* __restrict__ w_off, const float* __restrict__ b_off,
                 const float* __restrict__ w_attn, const float* __restrict__ b_attn,
                 const float* __restrict__ w_val, const float* __restrict__ b_val,
                 const float* __restrict__ w_out,
                 unsigned short* __restrict__ wcat_bf, unsigned short* __restrict__ wauxlo,
                 unsigned short* __restrict__ wout_bf, float* __restrict__ bcat)
{
    int i = blockIdx.x * 256 + threadIdx.x;
    if (i < 384 * 256) {
        int n = i >> 8, k = i & 255;
        float v;
        if (n < 256)      v = w_val[n * 256 + k];
        else if (n < 320) v = w_off[(n - 256) * 256 + k];
        else if (n < 352) v = w_attn[(n - 320) * 256 + k];
        else              v = 0.0f;
        unsigned short hi = f2bf(v);
        wcat_bf[i] = hi;
        if (n >= 256) wauxlo[(n - 256) * 256 + k] = f2bf(v - bf2f(hi));
    }
    if (i < 256 * 256) wout_bf[i] = f2bf(w_out[i]);
    if (i < 512) {
        float v = 0.0f;
        if (i < 256)      v = b_val[i];
        else if (i < 320) v = b_off[i - 256];
        else if (i < 352) v = b_attn[i - 320];
        bcat[i] = v;
    }
}

// ---------------------------------------------------------------------------
// Transpose x: fp32 [b][c][4096] -> bf16 [b][p][256]
// ---------------------------------------------------------------------------
__global__ __launch_bounds__(256)
void transpose_kernel(const float* __restrict__ x, unsigned short* __restrict__ xhi)
{
    __shared__ float t[64][65];
    const int bid = blockIdx.x;
    const int pt = bid & 63, ct = (bid >> 6) & 3, b = bid >> 8;
    const int tid = threadIdx.x;
    const int rr = tid >> 4, c4 = (tid & 15) * 4;

    const float* src = x + ((size_t)(b * 256 + ct * 64)) * HW + pt * 64;
#pragma unroll
    for (int j = 0; j < 4; ++j) {
        float4 v = *(const float4*)&src[(size_t)(j * 16 + rr) * HW + c4];
        t[j * 16 + rr][c4 + 0] = v.x; t[j * 16 + rr][c4 + 1] = v.y;
        t[j * 16 + rr][c4 + 2] = v.z; t[j * 16 + rr][c4 + 3] = v.w;
    }
    __syncthreads();

    const size_t obase = ((size_t)b * HW + pt * 64) * 256 + ct * 64;
#pragma unroll
    for (int j = 0; j < 4; ++j) {
        int p = j * 16 + rr;
        ushort4 hi = make_ushort4(f2bf(t[c4 + 0][p]), f2bf(t[c4 + 1][p]),
                                  f2bf(t[c4 + 2][p]), f2bf(t[c4 + 3][p]));
        *(ushort4*)&xhi[obase + (size_t)p * 256 + c4] = hi;
    }
}

// ---------------------------------------------------------------------------
// Unified projection: value (mt=0,1) + offsets/attn (mt=2, weight-split 2-pass).
// BK=256 single-shot staging: both panels are contiguous 64KB global spans.
// grid = 8(b) * 3(mt) * 32(pt) = 768, pt fastest (A-panel L2 reuse).
// off_ws -> [b][p][64], attn_ws -> [b][p][32] (float4-coalesced epilogue).
// ---------------------------------------------------------------------------
__global__ __launch_bounds__(256)
void proj_kernel(const unsigned short* __restrict__ wcat_bf, const unsigned short* __restrict__ wauxlo,
                 const unsigned short* __restrict__ xhi, const float* __restrict__ bcat,
                 unsigned short* __restrict__ value_bf,
                 float* __restrict__ off_ws, float* __restrict__ attn_ws)
{
    __shared__ unsigned short smem[2 * 128 * 256];   // 128 KB
    unsigned short* Al = smem;
    unsigned short* Bl = smem + 128 * 256;

    const int bid = blockIdx.x;
    const int pt = bid & 31;
    const int mt = (bid >> 5) % 3;
    const int b  = bid / 96;
    const int tid = threadIdx.x, wid = tid >> 6, lane = tid & 63;
    const int wm = wid >> 1, wn = wid & 1;
    const int mloc = lane & 15, ksel = lane >> 4;

    stage_panel(xhi + ((size_t)b * HW + pt * 128) * 256, Bl, wid, lane);

    f32x4 acc[4][4];
#pragma unroll
    for (int fm = 0; fm < 4; ++fm) {
        float4 bv = *(const float4*)&bcat[mt * 128 + wm * 64 + fm * 16 + ksel * 4];
#pragma unroll
        for (int fn = 0; fn < 4; ++fn) acc[fm][fn] = (f32x4){bv.x, bv.y, bv.z, bv.w};
    }

    if (mt < 2) {
        stage_panel(wcat_bf + mt * 128 * 256, Al, wid, lane);
        __syncthreads();
        compute_pass(Al, Bl, wm, wn, mloc, ksel, acc);

        // value epilogue: value_bf[(b*8+head)][p][c32]
#pragma unroll
        for (int fm = 0; fm < 4; ++fm) {
            const int ch = mt * 128 + wm * 64 + fm * 16 + ksel * 4;
            const int head = ch >> 5, c32 = ch & 31;
#pragma unroll
            for (int fn = 0; fn < 4; ++fn) {
                const int p = pt * 128 + wn * 64 + fn * 16 + mloc;
                f32x4 v = acc[fm][fn];
                ushort4 st = make_ushort4(f2bf(v[0]), f2bf(v[1]), f2bf(v[2]), f2bf(v[3]));
                *(ushort4*)&value_bf[(((size_t)(b * 8 + head)) * HW + p) * 32 + c32] = st;
            }
        }
    } else {
        stage_panel(wcat_bf + 256 * 256, Al, wid, lane);     // aux hi rows
        __syncthreads();
        compute_pass(Al, Bl, wm, wn, mloc, ksel, acc);
        __syncthreads();                                     // all reads of Al done
        stage_panel(wauxlo, Al, wid, lane);                  // aux lo rows
        __syncthreads();
        compute_pass(Al, Bl, wm, wn, mloc, ksel, acc);

        // aux epilogue: rows <64 -> off[b][p][64], rows 64-95 -> attn[b][p][32]
#pragma unroll
        for (int fm = 0; fm < 4; ++fm) {
            const int ch0 = wm * 64 + fm * 16 + ksel * 4;
#pragma unroll
            for (int fn = 0; fn < 4; ++fn) {
                const int p = pt * 128 + wn * 64 + fn * 16 + mloc;
                f32x4 v = acc[fm][fn];
                if (ch0 < 64) {
                    *(float4*)&off_ws[((size_t)b * HW + p) * 64 + ch0] =
                        make_float4(v[0], v[1], v[2], v[3]);
                } else if (ch0 < 96) {
                    *(float4*)&attn_ws[((size_t)b * HW + p) * 32 + (ch0 - 64)] =
                        make_float4(v[0], v[1], v[2], v[3]);
                }
            }
        }
    }
}

// ---------------------------------------------------------------------------
// Sampling: softmax(P=4) + bilinear gather + weighted sum.
// 8 lanes/position. Writes bf16 wgt_t[b][p][256]. grid = 8192
// ---------------------------------------------------------------------------
__global__ __launch_bounds__(256)
void sample_kernel(const unsigned short* __restrict__ value_bf, const float* __restrict__ off_ws,
                   const float* __restrict__ attn_ws, unsigned short* __restrict__ wgt_t)
{
    const int bid    = blockIdx.x;
    const int ptile  = bid & 127;
    const int head   = (bid >> 7) & 7;
    const int b      = bid >> 10;
    const int tid    = threadIdx.x;
    const int c4     = tid & 7;
    const int posIdx = tid >> 3;
    const int p      = ptile * 32 + posIdx;
    const int h      = p >> 6;
    const int w      = p & 63;

    const float gx = w * (2.0f / 63.0f) - 1.0f;
    const float gy = h * (2.0f / 63.0f) - 1.0f;

    float4 la = *(const float4*)&attn_ws[((size_t)b * HW + p) * 32 + head * 4];
    float m  = fmaxf(fmaxf(la.x, la.y), fmaxf(la.z, la.w));
    float e0 = __expf(la.x - m), e1 = __expf(la.y - m), e2 = __expf(la.z - m), e3 = __expf(la.w - m);
    float inv = 1.0f / (e0 + e1 + e2 + e3);
    float aw[4] = {e0 * inv, e1 * inv, e2 * inv, e3 * inv};

    float4 acc = make_float4(0.f, 0.f, 0.f, 0.f);
    const unsigned short* vb = value_bf + (size_t)(b * 8 + head) * HW * 32 + c4 * 4;
    const float* offp = off_ws + ((size_t)b * HW + p) * 64 + head * 8;

#pragma unroll
    for (int pt = 0; pt < 4; ++pt) {
        float ox = offp[pt * 2 + 0];
        float oy = offp[pt * 2 + 1];
        float ix = (gx + ox + 1.0f) * 31.5f;
        float iy = (gy + oy + 1.0f) * 31.5f;
        float x0f = floorf(ix), y0f = floorf(iy);
        float wx1 = ix - x0f, wx0 = 1.0f - wx1;
        float wy1 = iy - y0f, wy0 = 1.0f - wy1;
        int x0 = (int)x0f, y0 = (int)y0f;
        int x1 = x0 + 1,   y1 = y0 + 1;
        float a = aw[pt];
        float vx0 = (x0 >= 0 && x0 <= 63) ? 1.f : 0.f;
        float vx1 = (x1 >= 0 && x1 <= 63) ? 1.f : 0.f;
        float vy0 = (y0 >= 0 && y0 <= 63) ? 1.f : 0.f;
        float vy1 = (y1 >= 0 && y1 <= 63) ? 1.f : 0.f;
        float w00 = a * wy0 * wx0 * vy0 * vx0;
        float w01 = a * wy0 * wx1 * vy0 * vx1;
        float w10 = a * wy1 * wx0 * vy1 * vx0;
        float w11 = a * wy1 * wx1 * vy1 * vx1;
        int cx0 = min(max(x0, 0), 63), cx1 = min(max(x1, 0), 63);
        int cy0 = min(max(y0, 0), 63), cy1 = min(max(y1, 0), 63);
        ushort4 u00 = *(const ushort4*)&vb[(size_t)(cy0 * 64 + cx0) * 32];
        ushort4 u01 = *(const ushort4*)&vb[(size_t)(cy0 * 64 + cx1) * 32];
        ushort4 u10 = *(const ushort4*)&vb[(size_t)(cy1 * 64 + cx0) * 32];
        ushort4 u11 = *(const ushort4*)&vb[(size_t)(cy1 * 64 + cx1) * 32];
        acc.x += w00 * bf2f(u00.x) + w01 * bf2f(u01.x) + w10 * bf2f(u10.x) + w11 * bf2f(u11.x);
        acc.y += w00 * bf2f(u00.y) + w01 * bf2f(u01.y) + w10 * bf2f(u10.y) + w11 * bf2f(u11.y);
        acc.z += w00 * bf2f(u00.z) + w01 * bf2f(u01.z) + w10 * bf2f(u10.z) + w11 * bf2f(u11.z);
        acc.w += w00 * bf2f(u00.w) + w01 * bf2f(u01.w) + w10 * bf2f(u10.w) + w11 * bf2f(u11.w);
    }

    ushort4 st = make_ushort4(f2bf(acc.x), f2bf(acc.y), f2bf(acc.z), f2bf(acc.w));
    *(ushort4*)&wgt_t[((size_t)b * HW + p) * 256 + head * 32 + c4 * 4] = st;
}

// ---------------------------------------------------------------------------
// GEMM2: output projection + bias + residual, BK=256 single-shot + LDS-transpose
// epilogue (512B-contiguous float4 out stores / x loads). grid = 512.
// ---------------------------------------------------------------------------
#define EPW 132
__global__ __launch_bounds__(256)
void outproj_gemm(const unsigned short* __restrict__ wout_bf, const unsigned short* __restrict__ wgt_t,
                  const float* __restrict__ b_out, const float* __restrict__ x,
                  float* __restrict__ out)
{
    __shared__ unsigned short smem[2 * 128 * 256];   // 128 KB
    unsigned short* Al = smem;
    unsigned short* Bl = smem + 128 * 256;

    const int bid = blockIdx.x;
    const int pt = bid & 31, mt = (bid >> 5) & 1, b = bid >> 6;
    const int tid = threadIdx.x, wid = tid >> 6, lane = tid & 63;
    const int wm = wid >> 1, wn = wid & 1;
    const int mloc = lane & 15, ksel = lane >> 4;

    stage_panel(wout_bf + mt * 128 * 256, Al, wid, lane);
    stage_panel(wgt_t + ((size_t)b * HW + pt * 128) * 256, Bl, wid, lane);

    f32x4 acc[4][4];
#pragma unroll
    for (int fm = 0; fm < 4; ++fm)
#pragma unroll
        for (int fn = 0; fn < 4; ++fn) acc[fm][fn] = (f32x4){0.f, 0.f, 0.f, 0.f};

    __syncthreads();
    compute_pass(Al, Bl, wm, wn, mloc, ksel, acc);
    __syncthreads();                                 // panels dead; reuse as fp32

    float* ep = (float*)smem;                        // [128][EPW] = 67.6 KB
#pragma unroll
    for (int fm = 0; fm < 4; ++fm) {
        const int o_loc = wm * 64 + fm * 16 + ksel * 4;
#pragma unroll
        for (int fn = 0; fn < 4; ++fn) {
            const int p_loc = wn * 64 + fn * 16 + mloc;
            f32x4 v = acc[fm][fn];
#pragma unroll
            for (int r = 0; r < 4; ++r) ep[(o_loc + r) * EPW + p_loc] = v[r];
        }
    }
    __syncthreads();

    const int p4 = (tid & 31) * 4;
    const int o0 = tid >> 5;                         // 0..7
    const size_t gbase = ((size_t)(b * 256 + mt * 128)) * HW + pt * 128;
#pragma unroll
    for (int it = 0; it < 16; ++it) {
        const int o = o0 + it * 8;
        float bo = b_out[mt * 128 + o];
        float4 v = *(const float4*)&ep[o * EPW + p4];
        const size_t gi = gbase + (size_t)o * HW + p4;
        float4 xv = *(const float4*)&x[gi];
        *(float4*)&out[gi] = make_float4(v.x + bo + xv.x, v.y + bo + xv.y,
                                         v.z + bo + xv.z, v.w + bo + xv.w);
    }
}

// ---------------------------------------------------------------------------
extern "C" void kernel_launch(void* const* d_in, const int* in_sizes, int n_in,
                              void* d_out, int out_size, void* d_ws, size_t ws_size,
                              hipStream_t stream)
{
    const float* x      = (const float*)d_in[0];
    const float* w_off  = (const float*)d_in[1];
    const float* b_off  = (const float*)d_in[2];
    const float* w_attn = (const float*)d_in[3];
    const float* b_attn = (const float*)d_in[4];
    const float* w_val  = (const float*)d_in[5];
    const float* b_val  = (const float*)d_in[6];
    const float* w_out  = (const float*)d_in[7];
    const float* b_out  = (const float*)d_in[8];
    float* out = (float*)d_out;

    char* ws = (char*)d_ws;
    unsigned short* wcat_bf = (unsigned short*)(ws + 0);          //  196608 B
    unsigned short* wauxlo  = (unsigned short*)(ws + 196608);     //   65536 B
    unsigned short* wout_bf = (unsigned short*)(ws + 262144);     //  131072 B
    float*          bcat    = (float*)(ws + 393216);              //    2048 B
    unsigned short* xhi     = (unsigned short*)(ws + 395264);     // 16777216 B
    unsigned short* val_bf  = (unsigned short*)(ws + 17172480);   // 16777216 B
    float*          off_ws  = (float*)(ws + 33949696);            //  8388608 B  [b][p][64]
    float*          attn_ws = (float*)(ws + 42338304);            //  4194304 B  [b][p][32]
    unsigned short* wgt_t   = (unsigned short*)(ws + 46532608);   // 16777216 B  [b][p][256]

    prep_kernel<<<384, 256, 0, stream>>>(w_off, b_off, w_attn, b_attn, w_val, b_val,
                                         w_out, wcat_bf, wauxlo, wout_bf, bcat);
    transpose_kernel<<<2048, 256, 0, stream>>>(x, xhi);
    proj_kernel<<<768, 256, 0, stream>>>(wcat_bf, wauxlo, xhi, bcat, val_bf, off_ws, attn_ws);
    sample_kernel<<<8192, 256, 0, stream>>>(val_bf, off_ws, attn_ws, wgt_t);
    outproj_gemm<<<512, 256, 0, stream>>>(wout_bf, wgt_t, b_out, x, out);
}

// Round 7
// 77.803 us; speedup vs baseline: 1.1671x; 1.0376x over previous
//
#include <hip/hip_runtime.h>
#include <cstddef>

#define HW 4096

typedef __attribute__((ext_vector_type(8))) short short8v;   // 8 bf16
typedef __attribute__((ext_vector_type(4))) float f32x4;     // 4 fp32

__device__ inline unsigned short f2bf(float f) {
    unsigned int u = __float_as_uint(f);
    u += 0x7FFFu + ((u >> 16) & 1u);
    return (unsigned short)(u >> 16);
}
__device__ inline float bf2f(unsigned short s) {
    return __uint_as_float(((unsigned int)s) << 16);
}

// ---------------------------------------------------------------------------
// Reg-staged tile movement for a [128 rows][64 bf16] tile (16 KB).
// Layout contract (matches read_frag): slot s (16B) of row r lives at byte
//   r*128 + ((s ^ (r&7)) << 4)
// Global loads are linear row-major [row][256] slices; write side swizzles.
// Per thread: 4 x 16B. Wave w covers rows 32w..32w+31.
// ---------------------------------------------------------------------------
__device__ inline void load_tile(const unsigned short* __restrict__ g, int kc,
                                 int wid, int lane, short8v r[4])
{
    const int s  = lane & 7;
    const int r8 = lane >> 3;                  // 0..7
    const unsigned short* src = g + kc + s * 8;
#pragma unroll
    for (int i = 0; i < 4; ++i) {
        const int row = wid * 32 + i * 8 + r8;
        r[i] = *(const short8v*)(src + row * 256);
    }
}

__device__ inline void store_tile(unsigned short* lds, int wid, int lane, const short8v r[4])
{
    const int s  = lane & 7;
    const int r8 = lane >> 3;
#pragma unroll
    for (int i = 0; i < 4; ++i) {
        const int row = wid * 32 + i * 8 + r8;
        *(short8v*)((char*)lds + row * 128 + ((s ^ (row & 7)) << 4)) = r[i];
    }
}

// read one MFMA fragment (8 bf16) from a [128][64] swizzled LDS tile.
// row = ... + (lane&15), so (lane&7) == row&7 and the XOR matches the store.
__device__ inline short8v read_frag(const unsigned short* lds, int row, int kbyte, int lane)
{
    const char* p = (const char*)lds + row * 128 + (kbyte ^ ((lane & 7) * 16));
    return *(const short8v*)p;
}

// ---------------------------------------------------------------------------
// Prep: bf16 weights (row-major), lo-plane for aux weight rows, fp32 biases.
// wcat_bf[384][256]: rows 0-255 w_val, 256-319 w_off, 320-351 w_attn, 352-383 zero
// ---------------------------------------------------------------------------
__global__ __launch_bounds__(256)
void prep_kernel(const float* __restrict__ w_off, const float* __restrict__ b_off,
                 const float* __restrict__ w_attn, const float* __restrict__ b_attn,
                 const float* __restrict__ w_val, const float* __restrict__ b_val,
                 const float* __restrict__ w_out,
                 unsigned short* __restrict__ wcat_bf, unsigned short* __restrict__ wauxlo,
                 unsigned short* __restrict__ wout_bf, float* __restrict__ bcat)
{
    int i = blockIdx.x * 256 + threadIdx.x;
    if (i < 384 * 256) {
        int n = i >> 8, k = i & 255;
        float v;
        if (n < 256)      v = w_val[n * 256 + k];
        else if (n < 320) v = w_off[(n - 256) * 256 + k];
        else if (n < 352) v = w_attn[(n - 320) * 256 + k];
        else              v = 0.0f;
        unsigned short hi = f2bf(v);
        wcat_bf[i] = hi;
        if (n >= 256) wauxlo[(n - 256) * 256 + k] = f2bf(v - bf2f(hi));
    }
    if (i < 256 * 256) wout_bf[i] = f2bf(w_out[i]);
    if (i < 512) {
        float v = 0.0f;
        if (i < 256)      v = b_val[i];
        else if (i < 320) v = b_off[i - 256];
        else if (i < 352) v = b_attn[i - 320];
        bcat[i] = v;
    }
}

// ---------------------------------------------------------------------------
// Transpose x: fp32 [b][c][4096] -> bf16 [b][p][256]
// ---------------------------------------------------------------------------
__global__ __launch_bounds__(256)
void transpose_kernel(const float* __restrict__ x, unsigned short* __restrict__ xhi)
{
    __shared__ float t[64][65];
    const int bid = blockIdx.x;
    const int pt = bid & 63, ct = (bid >> 6) & 3, b = bid >> 8;
    const int tid = threadIdx.x;
    const int rr = tid >> 4, c4 = (tid & 15) * 4;

    const float* src = x + ((size_t)(b * 256 + ct * 64)) * HW + pt * 64;
#pragma unroll
    for (int j = 0; j < 4; ++j) {
        float4 v = *(const float4*)&src[(size_t)(j * 16 + rr) * HW + c4];
        t[j * 16 + rr][c4 + 0] = v.x; t[j * 16 + rr][c4 + 1] = v.y;
        t[j * 16 + rr][c4 + 2] = v.z; t[j * 16 + rr][c4 + 3] = v.w;
    }
    __syncthreads();

    const size_t obase = ((size_t)b * HW + pt * 64) * 256 + ct * 64;
#pragma unroll
    for (int j = 0; j < 4; ++j) {
        int p = j * 16 + rr;
        ushort4 hi = make_ushort4(f2bf(t[c4 + 0][p]), f2bf(t[c4 + 1][p]),
                                  f2bf(t[c4 + 2][p]), f2bf(t[c4 + 3][p]));
        *(ushort4*)&xhi[obase + (size_t)p * 256 + c4] = hi;
    }
}

// ---------------------------------------------------------------------------
// Unified projection: value (mt=0,1) + offsets/attn (mt=2, weight-split).
// Reg-staged: global->VGPR->swizzled ds_write. BK=64, 4 chunks; next chunk's
// global loads issued before current chunk's MFMA (latency hides under compute).
// grid = 8(b) * 3(mt) * 32(pt) = 768, 48KB LDS -> 3 blocks/CU.
// ---------------------------------------------------------------------------
__global__ __launch_bounds__(256)
void proj_kernel(const unsigned short* __restrict__ wcat_bf, const unsigned short* __restrict__ wauxlo,
                 const unsigned short* __restrict__ xhi, const float* __restrict__ bcat,
                 unsigned short* __restrict__ value_bf,
                 float* __restrict__ off_ws, float* __restrict__ attn_ws)
{
    __shared__ unsigned short lds[3 * 128 * 64];   // 48 KB
    unsigned short* Al  = lds;
    unsigned short* Bl  = lds + 128 * 64;
    unsigned short* Alo = lds + 2 * 128 * 64;

    const int bid = blockIdx.x;
    const int pt = bid & 31;
    const int mt = (bid >> 5) % 3;
    const int b  = bid / 96;
    const int tid = threadIdx.x, wid = tid >> 6, lane = tid & 63;
    const int wm = wid >> 1, wn = wid & 1;
    const int mloc = lane & 15, ksel = lane >> 4;

    const unsigned short* Bg = xhi + ((size_t)b * HW + pt * 128) * 256;

    f32x4 acc[4][4];
#pragma unroll
    for (int fm = 0; fm < 4; ++fm) {
        float4 bv = *(const float4*)&bcat[mt * 128 + wm * 64 + fm * 16 + ksel * 4];
#pragma unroll
        for (int fn = 0; fn < 4; ++fn) acc[fm][fn] = (f32x4){bv.x, bv.y, bv.z, bv.w};
    }

    if (mt < 2) {
        // ---- value path: 2 tiles per chunk ----
        const unsigned short* Ag = wcat_bf + mt * 128 * 256;
        short8v rA[4], rB[4];
        load_tile(Ag, 0, wid, lane, rA);
        load_tile(Bg, 0, wid, lane, rB);
#pragma unroll
        for (int kc = 0; kc < 4; ++kc) {
            if (kc) __syncthreads();
            store_tile(Al, wid, lane, rA);
            store_tile(Bl, wid, lane, rB);
            __syncthreads();
            if (kc < 3) {
                load_tile(Ag, (kc + 1) * 64, wid, lane, rA);
                load_tile(Bg, (kc + 1) * 64, wid, lane, rB);
            }
#pragma unroll
            for (int kk = 0; kk < 2; ++kk) {
                const int kb = kk * 64 + ksel * 16;
                short8v a[4], bb[4];
#pragma unroll
                for (int f = 0; f < 4; ++f) a[f]  = read_frag(Al, wm * 64 + f * 16 + mloc, kb, lane);
#pragma unroll
                for (int f = 0; f < 4; ++f) bb[f] = read_frag(Bl, wn * 64 + f * 16 + mloc, kb, lane);
#pragma unroll
                for (int fm = 0; fm < 4; ++fm)
#pragma unroll
                    for (int fn = 0; fn < 4; ++fn)
                        acc[fm][fn] = __builtin_amdgcn_mfma_f32_16x16x32_bf16(a[fm], bb[fn], acc[fm][fn], 0, 0, 0);
            }
        }
        // value epilogue: value_bf[(b*8+head)][p][c32]
#pragma unroll
        for (int fm = 0; fm < 4; ++fm) {
            const int ch = mt * 128 + wm * 64 + fm * 16 + ksel * 4;
            const int head = ch >> 5, c32 = ch & 31;
#pragma unroll
            for (int fn = 0; fn < 4; ++fn) {
                const int p = pt * 128 + wn * 64 + fn * 16 + mloc;
                f32x4 v = acc[fm][fn];
                ushort4 st = make_ushort4(f2bf(v[0]), f2bf(v[1]), f2bf(v[2]), f2bf(v[3]));
                *(ushort4*)&value_bf[(((size_t)(b * 8 + head)) * HW + p) * 32 + c32] = st;
            }
        }
    } else {
        // ---- aux path: (Wh + Wl) x Xbf, 3 tiles per chunk ----
        const unsigned short* Ahg = wcat_bf + 256 * 256;
        const unsigned short* Alg = wauxlo;
        short8v rA[4], rL[4], rB[4];
        load_tile(Ahg, 0, wid, lane, rA);
        load_tile(Alg, 0, wid, lane, rL);
        load_tile(Bg, 0, wid, lane, rB);
#pragma unroll
        for (int kc = 0; kc < 4; ++kc) {
            if (kc) __syncthreads();
            store_tile(Al, wid, lane, rA);
            store_tile(Alo, wid, lane, rL);
            store_tile(Bl, wid, lane, rB);
            __syncthreads();
            if (kc < 3) {
                load_tile(Ahg, (kc + 1) * 64, wid, lane, rA);
                load_tile(Alg, (kc + 1) * 64, wid, lane, rL);
                load_tile(Bg, (kc + 1) * 64, wid, lane, rB);
            }
#pragma unroll
            for (int kk = 0; kk < 2; ++kk) {
                const int kb = kk * 64 + ksel * 16;
                short8v ah[4], al[4], bb[4];
#pragma unroll
                for (int f = 0; f < 4; ++f) {
                    ah[f] = read_frag(Al,  wm * 64 + f * 16 + mloc, kb, lane);
                    al[f] = read_frag(Alo, wm * 64 + f * 16 + mloc, kb, lane);
                    bb[f] = read_frag(Bl,  wn * 64 + f * 16 + mloc, kb, lane);
                }
#pragma unroll
                for (int fm = 0; fm < 4; ++fm)
#pragma unroll
                    for (int fn = 0; fn < 4; ++fn) {
                        acc[fm][fn] = __builtin_amdgcn_mfma_f32_16x16x32_bf16(ah[fm], bb[fn], acc[fm][fn], 0, 0, 0);
                        acc[fm][fn] = __builtin_amdgcn_mfma_f32_16x16x32_bf16(al[fm], bb[fn], acc[fm][fn], 0, 0, 0);
                    }
            }
        }
        // aux epilogue: rows <64 -> off[b][p][64], rows 64-95 -> attn[b][p][32]
#pragma unroll
        for (int fm = 0; fm < 4; ++fm) {
            const int ch0 = wm * 64 + fm * 16 + ksel * 4;
#pragma unroll
            for (int fn = 0; fn < 4; ++fn) {
                const int p = pt * 128 + wn * 64 + fn * 16 + mloc;
                f32x4 v = acc[fm][fn];
                if (ch0 < 64) {
                    *(float4*)&off_ws[((size_t)b * HW + p) * 64 + ch0] =
                        make_float4(v[0], v[1], v[2], v[3]);
                } else if (ch0 < 96) {
                    *(float4*)&attn_ws[((size_t)b * HW + p) * 32 + (ch0 - 64)] =
                        make_float4(v[0], v[1], v[2], v[3]);
                }
            }
        }
    }
}

// ---------------------------------------------------------------------------
// Sampling: softmax(P=4) + bilinear gather + weighted sum.
// 8 lanes/position. Writes bf16 wgt_t[b][p][256]. grid = 8192
// ---------------------------------------------------------------------------
__global__ __launch_bounds__(256)
void sample_kernel(const unsigned short* __restrict__ value_bf, const float* __restrict__ off_ws,
                   const float* __restrict__ attn_ws, unsigned short* __restrict__ wgt_t)
{
    const int bid    = blockIdx.x;
    const int ptile  = bid & 127;
    const int head   = (bid >> 7) & 7;
    const int b      = bid >> 10;
    const int tid    = threadIdx.x;
    const int c4     = tid & 7;
    const int posIdx = tid >> 3;
    const int p      = ptile * 32 + posIdx;
    const int h      = p >> 6;
    const int w      = p & 63;

    const float gx = w * (2.0f / 63.0f) - 1.0f;
    const float gy = h * (2.0f / 63.0f) - 1.0f;

    float4 la = *(const float4*)&attn_ws[((size_t)b * HW + p) * 32 + head * 4];
    float m  = fmaxf(fmaxf(la.x, la.y), fmaxf(la.z, la.w));
    float e0 = __expf(la.x - m), e1 = __expf(la.y - m), e2 = __expf(la.z - m), e3 = __expf(la.w - m);
    float inv = 1.0f / (e0 + e1 + e2 + e3);
    float aw[4] = {e0 * inv, e1 * inv, e2 * inv, e3 * inv};

    float4 acc = make_float4(0.f, 0.f, 0.f, 0.f);
    const unsigned short* vb = value_bf + (size_t)(b * 8 + head) * HW * 32 + c4 * 4;
    const float* offp = off_ws + ((size_t)b * HW + p) * 64 + head * 8;

#pragma unroll
    for (int pt = 0; pt < 4; ++pt) {
        float ox = offp[pt * 2 + 0];
        float oy = offp[pt * 2 + 1];
        float ix = (gx + ox + 1.0f) * 31.5f;
        float iy = (gy + oy + 1.0f) * 31.5f;
        float x0f = floorf(ix), y0f = floorf(iy);
        float wx1 = ix - x0f, wx0 = 1.0f - wx1;
        float wy1 = iy - y0f, wy0 = 1.0f - wy1;
        int x0 = (int)x0f, y0 = (int)y0f;
        int x1 = x0 + 1,   y1 = y0 + 1;
        float a = aw[pt];
        float vx0 = (x0 >= 0 && x0 <= 63) ? 1.f : 0.f;
        float vx1 = (x1 >= 0 && x1 <= 63) ? 1.f : 0.f;
        float vy0 = (y0 >= 0 && y0 <= 63) ? 1.f : 0.f;
        float vy1 = (y1 >= 0 && y1 <= 63) ? 1.f : 0.f;
        float w00 = a * wy0 * wx0 * vy0 * vx0;
        float w01 = a * wy0 * wx1 * vy0 * vx1;
        float w10 = a * wy1 * wx0 * vy1 * vx0;
        float w11 = a * wy1 * wx1 * vy1 * vx1;
        int cx0 = min(max(x0, 0), 63), cx1 = min(max(x1, 0), 63);
        int cy0 = min(max(y0, 0), 63), cy1 = min(max(y1, 0), 63);
        ushort4 u00 = *(const ushort4*)&vb[(size_t)(cy0 * 64 + cx0) * 32];
        ushort4 u01 = *(const ushort4*)&vb[(size_t)(cy0 * 64 + cx1) * 32];
        ushort4 u10 = *(const ushort4*)&vb[(size_t)(cy1 * 64 + cx0) * 32];
        ushort4 u11 = *(const ushort4*)&vb[(size_t)(cy1 * 64 + cx1) * 32];
        acc.x += w00 * bf2f(u00.x) + w01 * bf2f(u01.x) + w10 * bf2f(u10.x) + w11 * bf2f(u11.x);
        acc.y += w00 * bf2f(u00.y) + w01 * bf2f(u01.y) + w10 * bf2f(u10.y) + w11 * bf2f(u11.y);
        acc.z += w00 * bf2f(u00.z) + w01 * bf2f(u01.z) + w10 * bf2f(u10.z) + w11 * bf2f(u11.z);
        acc.w += w00 * bf2f(u00.w) + w01 * bf2f(u01.w) + w10 * bf2f(u10.w) + w11 * bf2f(u11.w);
    }

    ushort4 st = make_ushort4(f2bf(acc.x), f2bf(acc.y), f2bf(acc.z), f2bf(acc.w));
    *(ushort4*)&wgt_t[((size_t)b * HW + p) * 256 + head * 32 + c4 * 4] = st;
}

// ---------------------------------------------------------------------------
// GEMM2: output projection + bias + residual, reg-staged, BK=64 loop.
// grid = 512, 32KB LDS. Coalesced 256B row stores with fp32 residual.
// ---------------------------------------------------------------------------
__global__ __launch_bounds__(256)
void outproj_gemm(const unsigned short* __restrict__ wout_bf, const unsigned short* __restrict__ wgt_t,
                  const float* __restrict__ b_out, const float* __restrict__ x,
                  float* __restrict__ out)
{
    __shared__ unsigned short Al[128 * 64];
    __shared__ unsigned short Bl[128 * 64];
    const int bid = blockIdx.x;
    const int pt = bid & 31, mt = (bid >> 5) & 1, b = bid >> 6;
    const int tid = threadIdx.x, wid = tid >> 6, lane = tid & 63;
    const int wm = wid >> 1, wn = wid & 1;
    const int mloc = lane & 15, ksel = lane >> 4;

    const unsigned short* Ag = wout_bf + mt * 128 * 256;
    const unsigned short* Bg = wgt_t + ((size_t)b * HW + pt * 128) * 256;

    f32x4 acc[4][4];
#pragma unroll
    for (int fm = 0; fm < 4; ++fm)
#pragma unroll
        for (int fn = 0; fn < 4; ++fn) acc[fm][fn] = (f32x4){0.f, 0.f, 0.f, 0.f};

    short8v rA[4], rB[4];
    load_tile(Ag, 0, wid, lane, rA);
    load_tile(Bg, 0, wid, lane, rB);
#pragma unroll
    for (int kc = 0; kc < 4; ++kc) {
        if (kc) __syncthreads();
        store_tile(Al, wid, lane, rA);
        store_tile(Bl, wid, lane, rB);
        __syncthreads();
        if (kc < 3) {
            load_tile(Ag, (kc + 1) * 64, wid, lane, rA);
            load_tile(Bg, (kc + 1) * 64, wid, lane, rB);
        }
#pragma unroll
        for (int kk = 0; kk < 2; ++kk) {
            const int kb = kk * 64 + ksel * 16;
            short8v a[4], bb[4];
#pragma unroll
            for (int f = 0; f < 4; ++f) a[f]  = read_frag(Al, wm * 64 + f * 16 + mloc, kb, lane);
#pragma unroll
            for (int f = 0; f < 4; ++f) bb[f] = read_frag(Bl, wn * 64 + f * 16 + mloc, kb, lane);
#pragma unroll
            for (int fm = 0; fm < 4; ++fm)
#pragma unroll
                for (int fn = 0; fn < 4; ++fn)
                    acc[fm][fn] = __builtin_amdgcn_mfma_f32_16x16x32_bf16(a[fm], bb[fn], acc[fm][fn], 0, 0, 0);
        }
    }

#pragma unroll
    for (int fm = 0; fm < 4; ++fm) {
        const int o = mt * 128 + wm * 64 + fm * 16 + ksel * 4;
        float4 bo = *(const float4*)&b_out[o];
#pragma unroll
        for (int fn = 0; fn < 4; ++fn) {
            const int p = pt * 128 + wn * 64 + fn * 16 + mloc;
            const size_t idx = ((size_t)(b * 256 + o)) * HW + p;
            f32x4 v = acc[fm][fn];
            out[idx + 0 * HW] = v[0] + bo.x + x[idx + 0 * HW];
            out[idx + 1 * HW] = v[1] + bo.y + x[idx + 1 * HW];
            out[idx + 2 * HW] = v[2] + bo.z + x[idx + 2 * HW];
            out[idx + 3 * HW] = v[3] + bo.w + x[idx + 3 * HW];
        }
    }
}

// ---------------------------------------------------------------------------
extern "C" void kernel_launch(void* const* d_in, const int* in_sizes, int n_in,
                              void* d_out, int out_size, void* d_ws, size_t ws_size,
                              hipStream_t stream)
{
    const float* x      = (const float*)d_in[0];
    const float* w_off  = (const float*)d_in[1];
    const float* b_off  = (const float*)d_in[2];
    const float* w_attn = (const float*)d_in[3];
    const float* b_attn = (const float*)d_in[4];
    const float* w_val  = (const float*)d_in[5];
    const float* b_val  = (const float*)d_in[6];
    const float* w_out  = (const float*)d_in[7];
    const float* b_out  = (const float*)d_in[8];
    float* out = (float*)d_out;

    char* ws = (char*)d_ws;
    unsigned short* wcat_bf = (unsigned short*)(ws + 0);          //  196608 B
    unsigned short* wauxlo  = (unsigned short*)(ws + 196608);     //   65536 B
    unsigned short* wout_bf = (unsigned short*)(ws + 262144);     //  131072 B
    float*          bcat    = (float*)(ws + 393216);              //    2048 B
    unsigned short* xhi     = (unsigned short*)(ws + 395264);     // 16777216 B
    unsigned short* val_bf  = (unsigned short*)(ws + 17172480);   // 16777216 B
    float*          off_ws  = (float*)(ws + 33949696);            //  8388608 B  [b][p][64]
    float*          attn_ws = (float*)(ws + 42338304);            //  4194304 B  [b][p][32]
    unsigned short* wgt_t   = (unsigned short*)(ws + 46532608);   // 16777216 B  [b][p][256]

    prep_kernel<<<384, 256, 0, stream>>>(w_off, b_off, w_attn, b_attn, w_val, b_val,
                                         w_out, wcat_bf, wauxlo, wout_bf, bcat);
    transpose_kernel<<<2048, 256, 0, stream>>>(x, xhi);
    proj_kernel<<<768, 256, 0, stream>>>(wcat_bf, wauxlo, xhi, bcat, val_bf, off_ws, attn_ws);
    sample_kernel<<<8192, 256, 0, stream>>>(val_bf, off_ws, attn_ws, wgt_t);
    outproj_gemm<<<512, 256, 0, stream>>>(wout_bf, wgt_t, b_out, x, out);
}